// Round 5
// baseline (393.739 us; speedup 1.0000x reference)
//
#include <hip/hip_runtime.h>

// MultiCellLSTM: B=4096 chains, H=64, T=512, types by t%4 = (0,2,1,2).
// R5: 512 threads = 8 waves = (slice p 0..3) x (row-half s 0..1), 2 waves/SIMD.
// Both waves of a pair compute the SAME full 12-MFMA gate tile for slice p
// (MFMA is cheap, ~60cyc issue); activation/update is split by row-half:
// wave (p,s) activates only acc rows 4q+2s..+1 (2 cells/lane, cx in regs)
// and writes those 2 hx rows. All 4 gates stay wave-local -> NO exchange,
// ONE barrier/step (R3 dataflow), but 2 independent waves/SIMD hide latency.
// Product-trick: si*tg=(1-Eg)*rcp(pi*pg), so*tanh(cx)=(1-Ec)*rcp(po*pc)
// (8 transcendentals/cell vs 10), clamped exponents for inf-safety.

typedef __attribute__((ext_vector_type(8))) short short8v;
typedef __attribute__((ext_vector_type(4))) float float4v;

template <int N> struct IC { static constexpr int value = N; };

#define AST 72   // shorts per A row (64 hx + pad); frags 16B aligned (AST%8==0)
#define XS1 516  // x LDS row strides (conflict-avoiding padding)
#define XS2 260
#define XS3 132

#if __has_builtin(__builtin_amdgcn_exp2f)
#define EXP2F(x) __builtin_amdgcn_exp2f(x)
#else
#define EXP2F(x) exp2f(x)
#endif
#if __has_builtin(__builtin_amdgcn_rcpf)
#define RCPF(x) __builtin_amdgcn_rcpf(x)
#else
#define RCPF(x) (1.0f / (x))
#endif

#define NL2E -1.4426950408889634f   // -log2(e)
#define NL2E2 -2.8853900817779268f  // -2*log2(e)

__device__ __forceinline__ short f2bf(float f) {
  union { float f; unsigned u; } v; v.f = f;
  unsigned r = v.u + 0x7FFFu + ((v.u >> 16) & 1u);  // RNE
  return (short)(r >> 16);
}
__device__ __forceinline__ float bf2f(short h) {
  union { float f; unsigned u; } v;
  v.u = ((unsigned)(unsigned short)h) << 16;
  return v.f;
}
__device__ __forceinline__ float rcp1p(float y) {  // 1/(1+exp2(y))
  return RCPF(1.0f + EXP2F(y));
}
__device__ __forceinline__ float fsig(float x) { return rcp1p(x * NL2E); }
__device__ __forceinline__ float clamp126(float y) {
  return fminf(fmaxf(y, -126.f), 126.f);  // v_med3_f32
}

__global__ __launch_bounds__(512, 2) void mlstm_kernel(
    const float* __restrict__ x1, const float* __restrict__ x2,
    const float* __restrict__ x3,
    const float* __restrict__ Wi3, const float* __restrict__ Wh3,
    const float* __restrict__ bi3, const float* __restrict__ bh3,
    const float* __restrict__ Wi2, const float* __restrict__ Wh2,
    const float* __restrict__ bi2, const float* __restrict__ bh2,
    const float* __restrict__ Wi1, const float* __restrict__ Wh1,
    const float* __restrict__ bi1, const float* __restrict__ bh1,
    const float* __restrict__ Wout, const float* __restrict__ bout,
    float* __restrict__ out) {
  __shared__ __attribute__((aligned(16))) short Ab0[16 * AST];
  __shared__ __attribute__((aligned(16))) short Ab1[16 * AST];
  __shared__ short x1b[16 * XS1];
  __shared__ short x2b[16 * XS2];
  __shared__ short x3b[16 * XS3];

  const int tid = threadIdx.x;  // 0..511
  const int wid = tid >> 6;     // 0..7
  const int lane = tid & 63;
  const int q = lane >> 4;
  const int c = lane & 15;
  const int p = wid & 3;   // col-slice
  const int s = wid >> 2;  // row-half: activates rows 4q+2s, 4q+2s+1
  const int R0 = blockIdx.x << 4;

  // ---- preload x into LDS as bf16 (padded strides) ----
  for (int idx = tid; idx < 16 * 512; idx += 512) {
    int m = idx >> 9, t = idx & 511;
    x1b[m * XS1 + t] = f2bf(x1[(size_t)(R0 + m) * 512 + t]);
  }
  for (int idx = tid; idx < 16 * 256; idx += 512) {
    int m = idx >> 8, t = idx & 255;
    x2b[m * XS2 + t] = f2bf(x2[(size_t)(R0 + m) * 256 + t]);
  }
  for (int idx = tid; idx < 16 * 128; idx += 512) {
    int m = idx >> 7, t = idx & 127;
    x3b[m * XS3 + t] = f2bf(x3[(size_t)(R0 + m) * 128 + t]);
  }
  // ---- A buffers: hx(t=0) = 0 ----
  for (int idx = tid; idx < 16 * AST; idx += 512) {
    Ab0[idx] = 0;
    Ab1[idx] = 0;
  }

  // ---- pack scaled weight fragments (4 gate tiles, n = g*64+16p+c) ----
  // B[k][n] = s_g * Wh[n][k], k = kf*32+q*8+j ; wix: k=64..66 -> Wi cols; bias f32.
  short8v whs[3][4][2];
  short8v wix[3][4];
  float bia[3][4];
  {
    const float* WhA[3] = {Wh3, Wh2, Wh1};
    const float* WiA[3] = {Wi3, Wi2, Wi1};
    const float* biA[3] = {bi3, bi2, bi1};
    const float* bhA[3] = {bh3, bh2, bh1};
    const int wdt[3] = {3, 2, 1};
#pragma unroll
    for (int ty = 0; ty < 3; ++ty) {
#pragma unroll
      for (int g = 0; g < 4; ++g) {
        const float sg = (g == 2) ? NL2E2 : NL2E;
        const int n = g * 64 + 16 * p + c;
#pragma unroll
        for (int kf = 0; kf < 2; ++kf) {
          short8v v;
#pragma unroll
          for (int j = 0; j < 8; ++j)
            v[j] = f2bf(sg * WhA[ty][n * 64 + kf * 32 + q * 8 + j]);
          whs[ty][g][kf] = v;
        }
        short8v v2 = {0, 0, 0, 0, 0, 0, 0, 0};
        if (q == 0) {
#pragma unroll
          for (int j = 0; j < 3; ++j)
            if (j < wdt[ty]) v2[j] = f2bf(sg * WiA[ty][n * wdt[ty] + j]);
        }
        wix[ty][g] = v2;
        bia[ty][g] = sg * (biA[ty][n] + bhA[ty][n]);
      }
    }
  }

  // addressing
  const int afo = c * AST + q * 8;                        // A-frag: m=c, k=q*8+j
  const int hwo = (4 * q + 2 * s) * AST + 16 * p + c;     // hx rows 4q+2s, +1
  const int x1o = c * XS1, x2o = c * XS2, x3o = c * XS3;

  __syncthreads();

  float cx[2] = {0.f, 0.f};

  auto stepf = [&](auto tyc, int t, const short* rbuf, short* wbuf) {
    constexpr int TY = decltype(tyc)::value;
    short hx1 = x1b[x1o + t];
    short hx2 = x2b[x2o + (t >> 1)];
    short hx3 = x3b[x3o + (t >> 2)];
    short8v a2 = {hx1, hx2, hx3, 0, 0, 0, 0, 0};
    short8v a0 = *(const short8v*)(rbuf + afo);
    short8v a1 = *(const short8v*)(rbuf + afo + 32);

    float4v acc[4];
#pragma unroll
    for (int g = 0; g < 4; ++g) {
      float b = bia[TY][g];
      float4v z = {b, b, b, b};
      z = __builtin_amdgcn_mfma_f32_16x16x32_bf16(a0, whs[TY][g][0], z, 0, 0, 0);
      z = __builtin_amdgcn_mfma_f32_16x16x32_bf16(a1, whs[TY][g][1], z, 0, 0, 0);
      z = __builtin_amdgcn_mfma_f32_16x16x32_bf16(a2, wix[TY][g], z, 0, 0, 0);
      acc[g] = z;
    }

    short* hb = wbuf + hwo;
#pragma unroll
    for (int rr = 0; rr < 2; ++rr) {
      const int ai = 2 * s + rr;
      float Ei = EXP2F(acc[0][ai]);            // e^{-i}
      float Ef = EXP2F(acc[1][ai]);            // e^{-f}
      float Eg = EXP2F(clamp126(acc[2][ai]));  // e^{-2g}
      float Eo = EXP2F(acc[3][ai]);            // e^{-o}
      // si*tg = (1-Eg) / ((1+Ei)(1+Eg)) ; sf = 1/(1+Ef)
      float sitg = (1.0f - Eg) * RCPF((1.0f + Ei) * (1.0f + Eg));
      float sf = RCPF(1.0f + Ef);
      float ncx = __builtin_fmaf(sf, cx[rr], sitg);
      cx[rr] = ncx;
      // so*tanh(ncx) = (1-Ec) / ((1+Eo)(1+Ec))
      float Ec = EXP2F(clamp126(ncx * NL2E2));
      float hv = (1.0f - Ec) * RCPF((1.0f + Eo) * (1.0f + Ec));
      hb[rr * AST] = f2bf(hv);
    }
    __syncthreads();
  };

  // t%4 -> type: 0->0, 1->2, 2->1, 3->2
  for (int t4 = 0; t4 < 512; t4 += 4) {
    stepf(IC<0>{}, t4, Ab0, Ab1);
    stepf(IC<2>{}, t4 + 1, Ab1, Ab0);
    stepf(IC<1>{}, t4 + 2, Ab0, Ab1);
    stepf(IC<2>{}, t4 + 3, Ab1, Ab0);
  }
  // final hx (after 512 steps) is in Ab0

  if (tid < 16) {
    float sum = bout[0];
    const short* hr = Ab0 + tid * AST;
#pragma unroll
    for (int k = 0; k < 64; ++k)
      sum = __builtin_fmaf(bf2f(hr[k]), Wout[k], sum);
    out[R0 + tid] = fsig(sum);
  }
}

extern "C" void kernel_launch(void* const* d_in, const int* in_sizes, int n_in,
                              void* d_out, int out_size, void* d_ws,
                              size_t ws_size, hipStream_t stream) {
  const float* x1 = (const float*)d_in[0];
  const float* x2 = (const float*)d_in[1];
  const float* x3 = (const float*)d_in[2];
  const float* Wi3 = (const float*)d_in[3];
  const float* Wh3 = (const float*)d_in[4];
  const float* bi3 = (const float*)d_in[5];
  const float* bh3 = (const float*)d_in[6];
  const float* Wi2 = (const float*)d_in[7];
  const float* Wh2 = (const float*)d_in[8];
  const float* bi2 = (const float*)d_in[9];
  const float* bh2 = (const float*)d_in[10];
  const float* Wi1 = (const float*)d_in[11];
  const float* Wh1 = (const float*)d_in[12];
  const float* bi1 = (const float*)d_in[13];
  const float* bh1 = (const float*)d_in[14];
  const float* Wout = (const float*)d_in[15];
  const float* bout = (const float*)d_in[16];
  float* out = (float*)d_out;

  hipLaunchKernelGGL(mlstm_kernel, dim3(256), dim3(512), 0, stream,
                     x1, x2, x3, Wi3, Wh3, bi3, bh3, Wi2, Wh2, bi2, bh2,
                     Wi1, Wh1, bi1, bh1, Wout, bout, out);
}

// Round 6
// 392.631 us; speedup vs baseline: 1.0028x; 1.0028x over previous
//
#include <hip/hip_runtime.h>

// MultiCellLSTM: B=4096 chains, H=64, T=512, types by t%4 = (0,2,1,2).
// R6 = R5 structure with the spill fixed via __launch_bounds__(512, 1):
// 512 threads = 8 waves = (slice p 0..3) x (row-half s 0..1), 2 waves/SIMD.
// Both waves of a pair compute the SAME full 12-MFMA gate tile for slice p
// (MFMA issue is cheap); activation/update is split by row-half: wave (p,s)
// activates only acc rows 4q+2s..+1 (2 cells/lane, cx in regs) and writes
// those 2 hx rows. All 4 gates stay wave-local -> NO exchange, ONE
// barrier/step (R3 dataflow), 2 independent waves/SIMD hide latency.
// R5 failed with (512,2): compiler capped at 128 VGPRs (4-waves/EU target)
// and spilled the 96-reg weight array to scratch (WRITE_SIZE 25 MB).
// (512,1) raises the cap to 256 which fits the ~175-reg working set.

typedef __attribute__((ext_vector_type(8))) short short8v;
typedef __attribute__((ext_vector_type(4))) float float4v;

template <int N> struct IC { static constexpr int value = N; };

#define AST 72   // shorts per A row (64 hx + pad); frags 16B aligned (AST%8==0)
#define XS1 516  // x LDS row strides (conflict-avoiding padding)
#define XS2 260
#define XS3 132

#if __has_builtin(__builtin_amdgcn_exp2f)
#define EXP2F(x) __builtin_amdgcn_exp2f(x)
#else
#define EXP2F(x) exp2f(x)
#endif
#if __has_builtin(__builtin_amdgcn_rcpf)
#define RCPF(x) __builtin_amdgcn_rcpf(x)
#else
#define RCPF(x) (1.0f / (x))
#endif

#define NL2E -1.4426950408889634f   // -log2(e)
#define NL2E2 -2.8853900817779268f  // -2*log2(e)

__device__ __forceinline__ short f2bf(float f) {
  union { float f; unsigned u; } v; v.f = f;
  unsigned r = v.u + 0x7FFFu + ((v.u >> 16) & 1u);  // RNE
  return (short)(r >> 16);
}
__device__ __forceinline__ float bf2f(short h) {
  union { float f; unsigned u; } v;
  v.u = ((unsigned)(unsigned short)h) << 16;
  return v.f;
}
__device__ __forceinline__ float rcp1p(float y) {  // 1/(1+exp2(y))
  return RCPF(1.0f + EXP2F(y));
}
__device__ __forceinline__ float fsig(float x) { return rcp1p(x * NL2E); }
__device__ __forceinline__ float clamp126(float y) {
  return fminf(fmaxf(y, -126.f), 126.f);  // v_med3_f32
}

__global__ __launch_bounds__(512, 1) void mlstm_kernel(
    const float* __restrict__ x1, const float* __restrict__ x2,
    const float* __restrict__ x3,
    const float* __restrict__ Wi3, const float* __restrict__ Wh3,
    const float* __restrict__ bi3, const float* __restrict__ bh3,
    const float* __restrict__ Wi2, const float* __restrict__ Wh2,
    const float* __restrict__ bi2, const float* __restrict__ bh2,
    const float* __restrict__ Wi1, const float* __restrict__ Wh1,
    const float* __restrict__ bi1, const float* __restrict__ bh1,
    const float* __restrict__ Wout, const float* __restrict__ bout,
    float* __restrict__ out) {
  __shared__ __attribute__((aligned(16))) short Ab0[16 * AST];
  __shared__ __attribute__((aligned(16))) short Ab1[16 * AST];
  __shared__ short x1b[16 * XS1];
  __shared__ short x2b[16 * XS2];
  __shared__ short x3b[16 * XS3];

  const int tid = threadIdx.x;  // 0..511
  const int wid = tid >> 6;     // 0..7
  const int lane = tid & 63;
  const int q = lane >> 4;
  const int c = lane & 15;
  const int p = wid & 3;   // col-slice
  const int s = wid >> 2;  // row-half: activates rows 4q+2s, 4q+2s+1
  const int R0 = blockIdx.x << 4;

  // ---- preload x into LDS as bf16 (padded strides) ----
  for (int idx = tid; idx < 16 * 512; idx += 512) {
    int m = idx >> 9, t = idx & 511;
    x1b[m * XS1 + t] = f2bf(x1[(size_t)(R0 + m) * 512 + t]);
  }
  for (int idx = tid; idx < 16 * 256; idx += 512) {
    int m = idx >> 8, t = idx & 255;
    x2b[m * XS2 + t] = f2bf(x2[(size_t)(R0 + m) * 256 + t]);
  }
  for (int idx = tid; idx < 16 * 128; idx += 512) {
    int m = idx >> 7, t = idx & 127;
    x3b[m * XS3 + t] = f2bf(x3[(size_t)(R0 + m) * 128 + t]);
  }
  // ---- A buffers: hx(t=0) = 0 ----
  for (int idx = tid; idx < 16 * AST; idx += 512) {
    Ab0[idx] = 0;
    Ab1[idx] = 0;
  }

  // ---- pack scaled weight fragments (4 gate tiles, n = g*64+16p+c) ----
  // B[k][n] = s_g * Wh[n][k], k = kf*32+q*8+j ; wix: k=64..66 -> Wi cols; bias f32.
  short8v whs[3][4][2];
  short8v wix[3][4];
  float bia[3][4];
  {
    const float* WhA[3] = {Wh3, Wh2, Wh1};
    const float* WiA[3] = {Wi3, Wi2, Wi1};
    const float* biA[3] = {bi3, bi2, bi1};
    const float* bhA[3] = {bh3, bh2, bh1};
    const int wdt[3] = {3, 2, 1};
#pragma unroll
    for (int ty = 0; ty < 3; ++ty) {
#pragma unroll
      for (int g = 0; g < 4; ++g) {
        const float sg = (g == 2) ? NL2E2 : NL2E;
        const int n = g * 64 + 16 * p + c;
#pragma unroll
        for (int kf = 0; kf < 2; ++kf) {
          short8v v;
#pragma unroll
          for (int j = 0; j < 8; ++j)
            v[j] = f2bf(sg * WhA[ty][n * 64 + kf * 32 + q * 8 + j]);
          whs[ty][g][kf] = v;
        }
        short8v v2 = {0, 0, 0, 0, 0, 0, 0, 0};
        if (q == 0) {
#pragma unroll
          for (int j = 0; j < 3; ++j)
            if (j < wdt[ty]) v2[j] = f2bf(sg * WiA[ty][n * wdt[ty] + j]);
        }
        wix[ty][g] = v2;
        bia[ty][g] = sg * (biA[ty][n] + bhA[ty][n]);
      }
    }
  }

  // addressing
  const int afo = c * AST + q * 8;                        // A-frag: m=c, k=q*8+j
  const int hwo = (4 * q + 2 * s) * AST + 16 * p + c;     // hx rows 4q+2s, +1
  const int x1o = c * XS1, x2o = c * XS2, x3o = c * XS3;

  __syncthreads();

  float cx[2] = {0.f, 0.f};

  auto stepf = [&](auto tyc, int t, const short* rbuf, short* wbuf) {
    constexpr int TY = decltype(tyc)::value;
    short hx1 = x1b[x1o + t];
    short hx2 = x2b[x2o + (t >> 1)];
    short hx3 = x3b[x3o + (t >> 2)];
    short8v a2 = {hx1, hx2, hx3, 0, 0, 0, 0, 0};
    short8v a0 = *(const short8v*)(rbuf + afo);
    short8v a1 = *(const short8v*)(rbuf + afo + 32);

    float4v acc[4];
#pragma unroll
    for (int g = 0; g < 4; ++g) {
      float b = bia[TY][g];
      float4v z = {b, b, b, b};
      z = __builtin_amdgcn_mfma_f32_16x16x32_bf16(a0, whs[TY][g][0], z, 0, 0, 0);
      z = __builtin_amdgcn_mfma_f32_16x16x32_bf16(a1, whs[TY][g][1], z, 0, 0, 0);
      z = __builtin_amdgcn_mfma_f32_16x16x32_bf16(a2, wix[TY][g], z, 0, 0, 0);
      acc[g] = z;
    }

    short* hb = wbuf + hwo;
#pragma unroll
    for (int rr = 0; rr < 2; ++rr) {
      const int ai = 2 * s + rr;
      float Ei = EXP2F(acc[0][ai]);            // e^{-i}
      float Ef = EXP2F(acc[1][ai]);            // e^{-f}
      float Eg = EXP2F(clamp126(acc[2][ai]));  // e^{-2g}
      float Eo = EXP2F(acc[3][ai]);            // e^{-o}
      // si*tg = (1-Eg) / ((1+Ei)(1+Eg)) ; sf = 1/(1+Ef)
      float sitg = (1.0f - Eg) * RCPF((1.0f + Ei) * (1.0f + Eg));
      float sf = RCPF(1.0f + Ef);
      float ncx = __builtin_fmaf(sf, cx[rr], sitg);
      cx[rr] = ncx;
      // so*tanh(ncx) = (1-Ec) / ((1+Eo)(1+Ec))
      float Ec = EXP2F(clamp126(ncx * NL2E2));
      float hv = (1.0f - Ec) * RCPF((1.0f + Eo) * (1.0f + Ec));
      hb[rr * AST] = f2bf(hv);
    }
    __syncthreads();
  };

  // t%4 -> type: 0->0, 1->2, 2->1, 3->2
  for (int t4 = 0; t4 < 512; t4 += 4) {
    stepf(IC<0>{}, t4, Ab0, Ab1);
    stepf(IC<2>{}, t4 + 1, Ab1, Ab0);
    stepf(IC<1>{}, t4 + 2, Ab0, Ab1);
    stepf(IC<2>{}, t4 + 3, Ab1, Ab0);
  }
  // final hx (after 512 steps) is in Ab0

  if (tid < 16) {
    float sum = bout[0];
    const short* hr = Ab0 + tid * AST;
#pragma unroll
    for (int k = 0; k < 64; ++k)
      sum = __builtin_fmaf(bf2f(hr[k]), Wout[k], sum);
    out[R0 + tid] = fsig(sum);
  }
}

extern "C" void kernel_launch(void* const* d_in, const int* in_sizes, int n_in,
                              void* d_out, int out_size, void* d_ws,
                              size_t ws_size, hipStream_t stream) {
  const float* x1 = (const float*)d_in[0];
  const float* x2 = (const float*)d_in[1];
  const float* x3 = (const float*)d_in[2];
  const float* Wi3 = (const float*)d_in[3];
  const float* Wh3 = (const float*)d_in[4];
  const float* bi3 = (const float*)d_in[5];
  const float* bh3 = (const float*)d_in[6];
  const float* Wi2 = (const float*)d_in[7];
  const float* Wh2 = (const float*)d_in[8];
  const float* bi2 = (const float*)d_in[9];
  const float* bh2 = (const float*)d_in[10];
  const float* Wi1 = (const float*)d_in[11];
  const float* Wh1 = (const float*)d_in[12];
  const float* bi1 = (const float*)d_in[13];
  const float* bh1 = (const float*)d_in[14];
  const float* Wout = (const float*)d_in[15];
  const float* bout = (const float*)d_in[16];
  float* out = (float*)d_out;

  hipLaunchKernelGGL(mlstm_kernel, dim3(256), dim3(512), 0, stream,
                     x1, x2, x3, Wi3, Wh3, bi3, bh3, Wi2, Wh2, bi2, bh2,
                     Wi1, Wh1, bi1, bh1, Wout, bout, out);
}